// Round 9
// baseline (266.814 us; speedup 1.0000x reference)
//
#include <hip/hip_runtime.h>
#include <math.h>

typedef _Float16 half8 __attribute__((ext_vector_type(8)));
typedef float f32x4 __attribute__((ext_vector_type(4)));

constexpr int kNFFT    = 1024;
constexpr int kHop     = 320;
constexpr int kMels    = 128;
constexpr int kFrames  = 1000;
constexpr int kBatch   = 32;
constexpr int kXLen    = 320000;
constexpr int kYLen    = kXLen - 1;          // 319999
constexpr int kYPad    = 328704;             // >= 1023*320+1024, mult of 2048
constexpr int kYOff    = 512;                // center-pad offset
constexpr float kPre   = 0.97f;
constexpr int kPStride = 544;                // power row stride (bins padded 513->544)
// Hann support: basis columns 112..911 nonzero -> k-steps 3..28 only
constexpr int kKsLo    = 3;
constexpr int kKsHi    = 28;                 // inclusive; 26 steps

// ws layout (offsets in _Float16 elements)
constexpr size_t kYLvl     = (size_t)kBatch * kYPad;            // halfs per level
constexpr size_t kFragLvl  = 64ull * 32 * 64 * 8;               // 1,048,576 halfs per level
constexpr size_t kFragOff  = 2 * kYLvl;                         // 21,037,056
constexpr size_t kMelFrOff = kFragOff + 2 * kFragLvl;           // 23,134,208
constexpr size_t kMelFrSz  = 8ull * 17 * 64 * 8;                // 69,632 halfs
constexpr size_t kPowOff   = kMelFrOff + kMelFrSz;              // 23,203,840

// fused prep grid partition
constexpr int kYJobBlks   = (kYPad / 8 + 255) / 256;            // 161
constexpr int kYJobTotal  = kYJobBlks * kBatch;                 // 5152
constexpr int kFragBlks   = 131072 / 256;                       // 512
constexpr int kMelBlks    = (8 * 17 * 64) / 256;                // 34
constexpr int kPrepGrid   = kYJobTotal + kFragBlks + kMelBlks;  // 5698

// ---- fused prep: y split / fourier frags (16x16 layout) / mel frags ----
__global__ void prep_all(const float* __restrict__ x, const float* __restrict__ basis,
                         const float* __restrict__ melb, _Float16* __restrict__ ws) {
    _Float16* ypad  = ws;
    _Float16* fr    = ws + kFragOff;
    _Float16* melfr = ws + kMelFrOff;
    const int bid = blockIdx.x;
    const int tid = threadIdx.x;

    if (bid < kYJobTotal) {
        // --- pre-emphasis + center pad, 2-level f16 split, 8 elems/thread ---
        int b = bid / kYJobBlks;
        int blk = bid - b * kYJobBlks;
        int e0 = (blk * 256 + tid) * 8;
        if (e0 >= kYPad) return;
        const float* xb = x + (size_t)b * kXLen;
        int yi = e0 - kYOff;
        float v[8];
        if (yi >= 0 && yi <= kXLen - 9) {
            float4 A = *(const float4*)(xb + yi);
            float4 B = *(const float4*)(xb + yi + 4);
            float C = xb[yi + 8];
            v[0] = A.y - kPre * A.x;  v[1] = A.z - kPre * A.y;
            v[2] = A.w - kPre * A.z;  v[3] = B.x - kPre * A.w;
            v[4] = B.y - kPre * B.x;  v[5] = B.z - kPre * B.y;
            v[6] = B.w - kPre * B.z;  v[7] = C   - kPre * B.w;
        } else {
            #pragma unroll
            for (int j = 0; j < 8; ++j) {
                int g = yi + j;
                v[j] = (g >= 0 && g < kYLen) ? xb[g + 1] - kPre * xb[g] : 0.0f;
            }
        }
        half8 hv, mv;
        #pragma unroll
        for (int j = 0; j < 8; ++j) {
            _Float16 h = (_Float16)v[j];
            hv[j] = h;
            mv[j] = (_Float16)(v[j] - (float)h);
        }
        size_t idx = (size_t)b * kYPad + e0;
        *(half8*)(ypad + idx) = hv;
        *(half8*)(ypad + idx + kYLvl) = mv;
    } else if (bid < kYJobTotal + kFragBlks) {
        // --- fourier basis -> 16x16x32 A-fragments, 2-level f16 split ---
        // packed rows: 0..512 cos bins 0..512; 513..1023 sin bins 1..511 (orig r+1)
        // frag[lv][g][ks][lane][j]: A[m=16g+(lane&15)][k=32ks+(lane>>4)*8+j]
        int id = (bid - kYJobTotal) * 256 + tid;   // < 131072
        int L  = id & 63;
        int ks = (id >> 6) & 31;
        int g  = id >> 11;                          // 0..63
        int r  = 16 * g + (L & 15);
        int orig = (r <= 512) ? r : r + 1;
        const float* src = basis + (size_t)orig * kNFFT + 32 * ks + (L >> 4) * 8;
        _Float16* dst = fr + (size_t)id * 8;        // id == (g*32+ks)*64+L
        #pragma unroll
        for (int j = 0; j < 8; ++j) {
            float a = src[j];
            _Float16 h = (_Float16)a;
            _Float16 m = (_Float16)(a - (float)h);
            dst[j] = h;
            dst[j + kFragLvl] = m;
        }
    } else {
        // --- mel basis -> 16x16x32 A-fragments, f16, K padded 513->544 ---
        int id = (bid - kYJobTotal - kFragBlks) * 256 + tid;
        if (id >= 8 * 17 * 64) return;
        int f = id / 1088;
        int rem = id - f * 1088;
        int ks = rem >> 6;
        int L = rem & 63;
        int m = 16 * f + (L & 15);
        int kb = 32 * ks + (L >> 4) * 8;
        _Float16* dst = melfr + (size_t)id * 8;
        #pragma unroll
        for (int j = 0; j < 8; ++j) {
            int k = kb + j;
            dst[j] = (k < 513) ? (_Float16)melb[(size_t)m * 513 + k] : (_Float16)0.0f;
        }
    }
}

// ---- main: 3-term split-f16 MFMA STFT + power ----
// NO LDS, NO barriers: every wave loads its A-fragments register-direct
// (L1 serves the 4-wave intra-block reuse), loads B direct, and free-runs.
// Fine-grained vmcnt waits + cross-block wave co-scheduling hide latency.
// block: (nt, g, b), 256 thr / 4 waves. wave tile M=128 x N=64 (nf=4).
// k-steps 3..28 only (window support). power[b][t(1024)][bin(544 pad)] f16.
__global__ __launch_bounds__(256, 2)
void stft_power(const _Float16* __restrict__ frags,
                const _Float16* __restrict__ ypad,
                _Float16* __restrict__ pw) {
    const int tid  = threadIdx.x;
    const int w    = tid >> 6;                            // 0..3
    const int lane = tid & 63;
    const int quad = lane >> 4;
    const int l16  = lane & 15;
    const int nt = blockIdx.x, g = blockIdx.y, b = blockIdx.z;
    const int t0 = nt * 256 + w * 64;
    const _Float16* yb0 = ypad + (size_t)b * kYPad;
    const _Float16* yb1 = yb0 + kYLvl;

    f32x4 acc[8][4] = {};

    // per-(f,lv) wave-uniform base + lane*8; advances 512 halfs per ks
    const _Float16* abase[2][8];
    #pragma unroll
    for (int lv = 0; lv < 2; ++lv)
        #pragma unroll
        for (int f = 0; f < 8; ++f) {
            int Gf = (f < 4) ? (4 * g + f) : (32 + 4 * g + (f - 4));
            abase[lv][f] = frags + (size_t)lv * kFragLvl
                         + ((size_t)(Gf * 32 + kKsLo) * 64 + lane) * 8;
        }
    const _Float16* bbase0[4];
    const _Float16* bbase1[4];
    #pragma unroll
    for (int nf = 0; nf < 4; ++nf) {
        int off = (t0 + nf * 16 + l16) * kHop + kKsLo * 32 + quad * 8;
        bbase0[nf] = yb0 + off;
        bbase1[nf] = yb1 + off;
    }

    for (int ks = kKsLo; ks <= kKsHi; ++ks) {
        half8 ah[8], am[8];
        #pragma unroll
        for (int f = 0; f < 8; ++f) {
            ah[f] = *(const half8*)abase[0][f];
            am[f] = *(const half8*)abase[1][f];
            abase[0][f] += 512;
            abase[1][f] += 512;
        }
        half8 bh[4], bm[4];
        #pragma unroll
        for (int nf = 0; nf < 4; ++nf) {
            bh[nf] = *(const half8*)bbase0[nf];
            bm[nf] = *(const half8*)bbase1[nf];
            bbase0[nf] += 32;
            bbase1[nf] += 32;
        }
        #pragma unroll
        for (int f = 0; f < 8; ++f) {
            #pragma unroll
            for (int nf = 0; nf < 4; ++nf) {
                f32x4 a = acc[f][nf];
                a = __builtin_amdgcn_mfma_f32_16x16x32_f16(ah[f], bh[nf], a, 0, 0, 0);
                a = __builtin_amdgcn_mfma_f32_16x16x32_f16(am[f], bh[nf], a, 0, 0, 0);
                a = __builtin_amdgcn_mfma_f32_16x16x32_f16(ah[f], bm[nf], a, 0, 0, 0);
                acc[f][nf] = a;
            }
        }
    }

    // epilogue: power = cos^2 + sin^2; chunk f (cos) pairs with f+4 (sin, same bin)
    #pragma unroll
    for (int mf = 0; mf < 4; ++mf) {
        int b0 = 64 * g + 16 * mf + 4 * quad;
        #pragma unroll
        for (int nf = 0; nf < 4; ++nf) {
            int t = t0 + nf * 16 + l16;
            size_t row = ((size_t)((b << 10) + t)) * kPStride;
            struct alignas(8) h4 { _Float16 v[4]; } pp;
            #pragma unroll
            for (int rr = 0; rr < 4; ++rr) {
                float pA = acc[mf][nf][rr];
                float pB = acc[4 + mf][nf][rr];
                float p2 = pA * pA + pB * pB;
                if (g == 0 && mf == 0 && quad == 0 && rr == 0) {
                    // packed row 0 = cos bin 0 (sin==0); paired row 512 = cos bin 512
                    p2 = pA * pA;
                    pw[row + 512] = (_Float16)(pB * pB);
                }
                pp.v[rr] = (_Float16)p2;
            }
            *(decltype(pp)*)&pw[row + b0] = pp;
        }
    }
}

// ---- mel + log via MFMA: out[b][m][t] = (log(mel+1e-5)+4.5)/5 ----
// block: (nt, b), 4 waves, wave covers 32 frames; M=128 mels, K=544.
__global__ __launch_bounds__(256)
void mel_mfma(const _Float16* __restrict__ melfr, const _Float16* __restrict__ pw,
              float* __restrict__ out) {
    const int tid  = threadIdx.x;
    const int w    = tid >> 6;
    const int lane = tid & 63;
    const int quad = lane >> 4;
    const int l16  = lane & 15;
    const int nt = blockIdx.x, b = blockIdx.y;
    const int t0 = nt * 128 + w * 32;

    f32x4 acc[8][2] = {};
    for (int ks = 0; ks < 17; ++ks) {
        half8 bp[2];
        #pragma unroll
        for (int nf = 0; nf < 2; ++nf) {
            int t = t0 + nf * 16 + l16;
            bp[nf] = *(const half8*)(pw + ((size_t)((b << 10) + t)) * kPStride
                                     + 32 * ks + quad * 8);
        }
        #pragma unroll
        for (int f = 0; f < 8; ++f) {
            half8 af = *(const half8*)(melfr + ((size_t)(f * 17 + ks) * 64 + lane) * 8);
            #pragma unroll
            for (int nf = 0; nf < 2; ++nf)
                acc[f][nf] = __builtin_amdgcn_mfma_f32_16x16x32_f16(af, bp[nf], acc[f][nf], 0, 0, 0);
        }
    }
    #pragma unroll
    for (int f = 0; f < 8; ++f) {
        #pragma unroll
        for (int nf = 0; nf < 2; ++nf) {
            int t = t0 + nf * 16 + l16;
            if (t < kFrames) {
                #pragma unroll
                for (int r = 0; r < 4; ++r) {
                    int m = 16 * f + 4 * quad + r;
                    out[((size_t)(b * kMels + m)) * kFrames + t] =
                        (__logf(acc[f][nf][r] + 1e-5f) + 4.5f) * 0.2f;
                }
            }
        }
    }
}

extern "C" void kernel_launch(void* const* d_in, const int* in_sizes, int n_in,
                              void* d_out, int out_size, void* d_ws, size_t ws_size,
                              hipStream_t stream) {
    const float* x     = (const float*)d_in[0];
    const float* basis = (const float*)d_in[1];
    const float* melb  = (const float*)d_in[2];
    float* out = (float*)d_out;

    _Float16* ws    = (_Float16*)d_ws;
    _Float16* frags = ws + kFragOff;
    _Float16* melfr = ws + kMelFrOff;
    _Float16* pw    = ws + kPowOff;

    prep_all<<<dim3(kPrepGrid), 256, 0, stream>>>(x, basis, melb, ws);
    stft_power<<<dim3(4, 8, kBatch), 256, 0, stream>>>(frags, ws, pw);
    mel_mfma<<<dim3(8, kBatch), 256, 0, stream>>>(melfr, pw, out);
}